// Round 7
// baseline (88.564 us; speedup 1.0000x reference)
//
#include <hip/hip_runtime.h>

// ---------------------------------------------------------------------------
// MaximumMeanDiscrepancy: BATCH=160, INSTANCES=4, FEAT=1024, P=40
// out[0] = mmd(wcs, wct), out[1] = mmd(bcs, bct)
// ---------------------------------------------------------------------------

#define FEAT   1024
#define NROW   160     // BATCH
#define NBC    6088    // (1 + 39*39) * 4
#define NWC    160

// workspace layout (float offsets). bci/wci are INTERLEAVED: row i is
// {source float4, target float4}. 256 pad rows of 1e19f follow each array so
// every strip can run full 256-wide (pad d -> huge -> all terms exact 0,
// never hot). The strip table (uint16, 151KB) lives at offset 0, overlapping
// the E matrices, which are DEAD after scatter; build_table runs after.
#define WS_ES   0          // E_s [160*160]   (later: strip table)
#define WS_ET   25600      // E_t [160*160]
#define WS_BCI  51200      // bci [(6088+256)*8]
#define WS_WCI  101952     // wci [(160+256)*8]
#define WS_ACC_BYTES 421120  // 6*64 doubles
#define NSLOT  64

// strip scheduling: equal strips of 256 j's.
// bc rows: C(i) prefix, 75432 strips; wc rows: 159; diag-bc: 24; diag-wc: 1.
#define BC_STRIPS   75432
#define WC_BASE     75432
#define DIAGBC_BASE 75591
#define DIAGWC_BASE 75615
#define NSTRIPS     75616
#define GK_GRID     1536   // 6 blocks/CU x 256 CUs: all co-resident, 1 round

struct Coef { float c[19]; };  // c[k] = -log2(e)/(2*sigma_k)  (exp2 form)

#if defined(__has_builtin)
#if __has_builtin(__builtin_amdgcn_exp2f)
#define EXP2(x) __builtin_amdgcn_exp2f(x)
#else
#define EXP2(x) exp2f(x)
#endif
#else
#define EXP2(x) exp2f(x)
#endif

// strips before bc row i: C(i) = 75432 - S(6087-i),
// S(M) = sum_{m=1..M} ceil(m/256) = 128*q*(q+1) + rem*(q+1), q=M>>8.
__device__ __forceinline__ int Cfun(int i) {
    int M = 6087 - i;
    int q = M >> 8, r = M & 255;
    return BC_STRIPS - (q * (q + 1) * 128 + r * (q + 1));
}

// --- kernel 1: E[a,b] = ||f_a - f_b||^2 for both sides, 16x16 tiles ---------
__global__ __launch_bounds__(256) void compute_E(const float* __restrict__ Fs,
                                                 const float* __restrict__ Ft,
                                                 float* __restrict__ ws) {
    int side = blockIdx.x / 100;          // 0 = source, 1 = target
    int tile = blockIdx.x % 100;
    int trow = tile / 10, tcol = tile % 10;
    const float* F = side ? Ft : Fs;
    float* E = ws + (side ? WS_ET : WS_ES);

    __shared__ float As[16][132];
    __shared__ float Bs[16][132];
    int tid = threadIdx.x;
    int ti = tid >> 4, tj = tid & 15;
    int lr = tid >> 5;        // 0..7
    int lc4 = tid & 31;       // float4 column (0..31) of 128-dim chunk

    float acc = 0.f;
    for (int ch = 0; ch < 8; ++ch) {
        for (int rr = lr; rr < 16; rr += 8) {
            float4 a = *(const float4*)(F + (trow*16+rr)*FEAT + ch*128 + lc4*4);
            *(float4*)(&As[rr][lc4*4]) = a;
            float4 b = *(const float4*)(F + (tcol*16+rr)*FEAT + ch*128 + lc4*4);
            *(float4*)(&Bs[rr][lc4*4]) = b;
        }
        __syncthreads();
        #pragma unroll
        for (int c = 0; c < 128; c += 4) {
            float4 a = *(const float4*)(&As[ti][c]);
            float4 b = *(const float4*)(&Bs[tj][c]);
            float d0 = a.x - b.x, d1 = a.y - b.y, d2 = a.z - b.z, d3 = a.w - b.w;
            acc = fmaf(d0, d0, acc);
            acc = fmaf(d1, d1, acc);
            acc = fmaf(d2, d2, acc);
            acc = fmaf(d3, d3, acc);
        }
        __syncthreads();
    }
    E[(trow*16+ti)*NROW + tcol*16 + tj] = acc;
}

// --- kernel 2: gather interleaved bci/wci rows; pad; zero accumulators ------
__global__ __launch_bounds__(256) void scatter(float* __restrict__ ws) {
    int idx = blockIdx.x * blockDim.x + threadIdx.x;
    const float* E_s = ws + WS_ES;
    const float* E_t = ws + WS_ET;
    float4* bci = (float4*)(ws + WS_BCI);
    float4* wci = (float4*)(ws + WS_WCI);
    double* accs = (double*)((char*)ws + WS_ACC_BYTES);

    if (idx < 6 * NSLOT) accs[idx] = 0.0;

    if (idx < NBC) {
        int t = idx >> 2, ii = idx & 3;
        int pi, pj;
        if (t == 0) { pi = 0; pj = 1; }
        else {
            int tt = t - 1;
            pi = 1 + tt / 39;
            int jj = tt % 39;
            pj = (jj < pi) ? jj : jj + 1;
        }
        bci[2*idx]   = *(const float4*)(E_s + (4*pi + ii)*NROW + 4*pj);
        bci[2*idx+1] = *(const float4*)(E_t + (4*pi + ii)*NROW + 4*pj);
    } else if (idx < NBC + NWC) {
        int r = idx - NBC;
        int p = r >> 2;
        wci[2*r]   = *(const float4*)(E_s + r*NROW + 4*p);
        wci[2*r+1] = *(const float4*)(E_t + r*NROW + 4*p);
    } else if (idx < NBC + NWC + 256) {
        int p = NBC + (idx - (NBC + NWC));
        float4 pad = make_float4(1e19f, 1e19f, 1e19f, 1e19f);
        bci[2*p] = pad;
        bci[2*p+1] = pad;
    } else if (idx < NBC + NWC + 512) {
        int p = NWC + (idx - (NBC + NWC + 256));
        float4 pad = make_float4(1e19f, 1e19f, 1e19f, 1e19f);
        wci[2*p] = pad;
        wci[2*p+1] = pad;
    }
}

// --- kernel 2b: build the strip table over the dead E region ----------------
// entry = type<<13 | rowfield. type 0=bc row, 1=wc row, 2=diag-bc, 3=diag-wc.
__global__ __launch_bounds__(256) void build_table(float* __restrict__ ws) {
    unsigned short* tab = (unsigned short*)ws;
    int idx = blockIdx.x * 256 + threadIdx.x;
    if (idx < 6088) {
        int Ci = Cfun(idx);
        int trips = (6342 - idx) >> 8;            // ceil((6087-idx)/256)
        for (int o = 0; o < trips; ++o) tab[Ci + o] = (unsigned short)idx;
    } else if (idx < 6088 + 159) {
        int r = idx - 6088;
        tab[WC_BASE + r] = (unsigned short)(0x2000 | r);
    } else if (idx < 6088 + 159 + 24) {
        int o = idx - 6247;
        tab[DIAGBC_BASE + o] = (unsigned short)(0x4000 | o);
    } else if (idx == 6271) {
        tab[DIAGWC_BASE] = (unsigned short)0x6000;
    }
}

// --- tail terms for hot pairs (d < 7280): sigma <= 35 tiers -----------------
// Tier-skip is exact: exp2(d*c) == 0.0f once d*c <= -150:
// sigma<=35 -> d>=7279; sigma<=15 -> d>=3120; sigma<=1 -> 208.
__device__ __forceinline__ float tail_sum(float d, const Coef& co) {
    float s = EXP2(d * co.c[10]) + EXP2(d * co.c[11])
            + EXP2(d * co.c[12]) + EXP2(d * co.c[13]);   // 20,25,30,35
    if (d < 3120.0f)
        s += EXP2(d * co.c[7]) + EXP2(d * co.c[8]) + EXP2(d * co.c[9]); // 5,10,15
    if (d < 208.0f)
        s += EXP2(d * co.c[0]) + EXP2(d * co.c[1]) + EXP2(d * co.c[2])
           + EXP2(d * co.c[3]) + EXP2(d * co.c[4]) + EXP2(d * co.c[5])
           + EXP2(d * co.c[6]);                           // sigma <= 1
    return s;
}

// x^10 = x2=x*x, x4=x2*x2, x5=x4*x, x10=x5*x5
__device__ __forceinline__ float pow10f(float x) {
    float x2 = x * x;
    float x4 = x2 * x2;
    float x5 = x4 * x;
    return x5 * x5;
}

// mandatory sigmas {100,1e3,1e4,1e5,1e6}: 2 hw exps + ^10 chains
// (1e5 = e6^10, 1e3 = e4^10, 100 = e3^10); chain rel-err <= ~1e-5.
__device__ __forceinline__ float mand(float d, const Coef& co) {
    float e6 = EXP2(d * co.c[18]);
    float e4 = EXP2(d * co.c[16]);
    float e5 = pow10f(e6);
    float e3 = pow10f(e4);
    float e100 = pow10f(e3);
    return ((e6 + e5) + (e4 + e3)) + e100;
}

__device__ __forceinline__ float sqd(float4 a, float4 b) {
    float d0 = a.x - b.x, d1 = a.y - b.y, d2 = a.z - b.z, d3 = a.w - b.w;
    float d = d0 * d0;
    d = fmaf(d1, d1, d);
    d = fmaf(d2, d2, d);
    return fmaf(d3, d3, d);
}

// --- kernel 3: strip-scheduled fused sweep ----------------------------------
// 1536 blocks (all co-resident), block b takes strips b, b+1536, ... Each bc/wc
// strip: rows {s_i,t_i} vs 256 j's -> 4 evals/pair (ss,tt,st,ts). Hot pairs
// (d<7280) go to 6 per-wave LDS queues (ballot+mbcnt), drained 64-wide dense.
// f32 partials per job (magnitude <= ~900, rms err ~1e-9 rel), one flush.
__global__ __launch_bounds__(256, 6) void gk_strips(float* __restrict__ ws, Coef co) {
    const unsigned short* tab = (const unsigned short*)ws;
    const float4* bci = (const float4*)(ws + WS_BCI);
    const float4* wci = (const float4*)(ws + WS_WCI);
    double* accs = (double*)((char*)ws + WS_ACC_BYTES);

    __shared__ float qb[4][6][192];
    __shared__ double wsum[4][6];
    int lane = threadIdx.x & 63, w = threadIdx.x >> 6;
    int qn0 = 0, qn1 = 0, qn2 = 0, qn3 = 0, qn4 = 0, qn5 = 0;
    float f0 = 0.f, f1 = 0.f, f2 = 0.f, f3 = 0.f, f4 = 0.f, f5 = 0.f;

#define MBCNT(m) __builtin_amdgcn_mbcnt_hi((unsigned)((m) >> 32), \
                  __builtin_amdgcn_mbcnt_lo((unsigned)(m), 0u))
#define PUSHQ(Q, QN, dv) { bool hot_ = (dv) < 7280.0f;              \
        unsigned long long m_ = __ballot(hot_);                      \
        if (hot_) qb[w][Q][(QN) + MBCNT(m_)] = (dv);                 \
        (QN) += (int)__popcll(m_); }
#define DRAINQ(Q, QN, ACC) if ((QN) >= 64) { (QN) -= 64;             \
        ACC += tail_sum(qb[w][Q][(QN) + lane], co); }

    auto body = [&](const float4* __restrict__ Yv, int row, int j0,
                    float& b0, float& b1, float& b2,
                    int qofs, int& c0, int& c1, int& c2) {
        float4 xs = Yv[2*row], xt = Yv[2*row+1];
        const float4* Yp = Yv + 2*(j0 + (int)threadIdx.x);
        float4 ys = Yp[0], yt = Yp[1];
        float dss = sqd(xs, ys), dtt = sqd(xt, yt);
        float dst = sqd(xs, yt), dts = sqd(xt, ys);
        b0 += mand(dss, co);
        b1 += mand(dtt, co);
        b2 += mand(dst, co) + mand(dts, co);
        PUSHQ(qofs+0, c0, dss); DRAINQ(qofs+0, c0, b0);
        PUSHQ(qofs+1, c1, dtt); DRAINQ(qofs+1, c1, b1);
        PUSHQ(qofs+2, c2, dst);
        PUSHQ(qofs+2, c2, dts); DRAINQ(qofs+2, c2, b2); DRAINQ(qofs+2, c2, b2);
    };

    for (int g = blockIdx.x; g < NSTRIPS; g += GK_GRID) {
        unsigned u = tab[g];
        int ty = u >> 13, rf = u & 0x1FFF;
        if (ty == 0) {                 // bc triangle strip
            int ord = g - Cfun(rf);
            body(bci, rf, rf + 1 + (ord << 8), f3, f4, f5, 3, qn3, qn4, qn5);
        } else if (ty == 1) {          // wc triangle strip
            body(wci, rf, rf + 1, f0, f1, f2, 0, qn0, qn1, qn2);
        } else if (ty == 2) {          // bc st-diagonal
            int idx0 = (rf << 8) + (int)threadIdx.x;
            if (idx0 < NBC) {
                float d = sqd(bci[2*idx0], bci[2*idx0+1]);
                float sv = mand(d, co);
                if (d < 7280.0f) sv += tail_sum(d, co);
                f5 += sv;
            }
        } else {                       // wc st-diagonal
            int idx0 = (int)threadIdx.x;
            if (idx0 < NWC) {
                float d = sqd(wci[2*idx0], wci[2*idx0+1]);
                float sv = mand(d, co);
                if (d < 7280.0f) sv += tail_sum(d, co);
                f2 += sv;
            }
        }
    }

    // flush remaining queue entries (< 64 each)
    if (lane < qn0) f0 += tail_sum(qb[w][0][lane], co);
    if (lane < qn1) f1 += tail_sum(qb[w][1][lane], co);
    if (lane < qn2) f2 += tail_sum(qb[w][2][lane], co);
    if (lane < qn3) f3 += tail_sum(qb[w][3][lane], co);
    if (lane < qn4) f4 += tail_sum(qb[w][4][lane], co);
    if (lane < qn5) f5 += tail_sum(qb[w][5][lane], co);

    double a0 = f0, a1 = f1, a2 = f2, a3 = f3, a4 = f4, a5 = f5;
    #pragma unroll
    for (int off = 32; off; off >>= 1) {
        a0 += __shfl_down(a0, off, 64);
        a1 += __shfl_down(a1, off, 64);
        a2 += __shfl_down(a2, off, 64);
        a3 += __shfl_down(a3, off, 64);
        a4 += __shfl_down(a4, off, 64);
        a5 += __shfl_down(a5, off, 64);
    }
    if (lane == 0) {
        wsum[w][0] = a0; wsum[w][1] = a1; wsum[w][2] = a2;
        wsum[w][3] = a3; wsum[w][4] = a4; wsum[w][5] = a5;
    }
    __syncthreads();
    if (threadIdx.x < 6) {
        int q = threadIdx.x;
        double tot = wsum[0][q] + wsum[1][q] + wsum[2][q] + wsum[3][q];
        atomicAdd(&accs[q * NSLOT + (blockIdx.x & (NSLOT - 1))], tot);
    }
#undef PUSHQ
#undef DRAINQ
#undef MBCNT
}

// --- kernel 4: combine into the two output scalars --------------------------
__global__ void finalize(const float* __restrict__ ws, float* __restrict__ out) {
    const double* accs = (const double*)((const char*)ws + WS_ACC_BYTES);
    int lane = threadIdx.x;  // blockDim = 64
    double p[6];
    #pragma unroll
    for (int q = 0; q < 6; ++q) {
        p[q] = accs[q * NSLOT + lane];
        #pragma unroll
        for (int off = 32; off; off >>= 1) p[q] += __shfl_down(p[q], off, 64);
    }
    if (lane == 0) {
        double t0 = 2.0 * p[0] + 19.0 * NWC;   // self: 2*triangle + diag
        double t1 = 2.0 * p[1] + 19.0 * NWC;
        double t3 = 2.0 * p[3] + 19.0 * NBC;
        double t4 = 2.0 * p[4] + 19.0 * NBC;
        double nw = (double)NWC * (double)NWC;
        double nb = (double)NBC * (double)NBC;
        out[0] = (float)((t0 + t1 - 2.0 * p[2]) / nw);   // p2 = full st sum
        out[1] = (float)((t3 + t4 - 2.0 * p[5]) / nb);
    }
}

extern "C" void kernel_launch(void* const* d_in, const int* in_sizes, int n_in,
                              void* d_out, int out_size, void* d_ws, size_t ws_size,
                              hipStream_t stream) {
    const float* src = (const float*)d_in[0];
    const float* tgt = (const float*)d_in[1];
    float* out = (float*)d_out;
    float* ws = (float*)d_ws;

    static const double SIG[19] = {1e-06, 1e-05, 1e-04, 1e-03, 1e-02, 1e-01,
                                   1.0, 5.0, 10.0, 15.0, 20.0, 25.0, 30.0,
                                   35.0, 100.0, 1e3, 1e4, 1e5, 1e6};
    Coef co;
    for (int k = 0; k < 19; ++k)
        co.c[k] = (float)(-1.0 / (2.0 * SIG[k] * 0.6931471805599453));  // -log2e/(2s)

    compute_E<<<200, 256, 0, stream>>>(src, tgt, ws);
    scatter<<<27, 256, 0, stream>>>(ws);
    build_table<<<25, 256, 0, stream>>>(ws);
    gk_strips<<<GK_GRID, 256, 0, stream>>>(ws, co);
    finalize<<<1, 64, 0, stream>>>(ws, out);
}

// Round 8
// 74.051 us; speedup vs baseline: 1.1960x; 1.1960x over previous
//
#include <hip/hip_runtime.h>

// ---------------------------------------------------------------------------
// MaximumMeanDiscrepancy: BATCH=160, INSTANCES=4, FEAT=1024, P=40
// out[0] = mmd(wcs, wct), out[1] = mmd(bcs, bct)
// ---------------------------------------------------------------------------

#define FEAT   1024
#define NROW   160     // BATCH
#define NBC    6088    // (1 + 39*39) * 4
#define NWC    160
#define GK_BLOCKS 1522 // 4 bc rows each, constant total length 12174

// workspace layout (float offsets). bci/wci are INTERLEAVED: row i is
// {source float4, target float4}. 256 pad rows of 1e19f follow each array so
// the j-loop runs a uniform trip count (pad d -> huge/inf -> table clamp gives
// ~1e-29, never hot).
#define WS_ES   0          // E_s [160*160]
#define WS_ET   25600      // E_t [160*160]
#define WS_BCI  51200      // bci [(6088+256)*8]
#define WS_WCI  101952     // wci [(160+256)*8]
#define WS_ACC_BYTES 421120  // 6*64 doubles
#define NSLOT  64

// PL table: s_big(d) = e6+e5+e4+e3 over d in [2^12, 2^27), 128 cells/octave,
// bits-indexed by (float_bits >> 16) - 17792. e2 (sigma=100) < 2e-23 for
// d >= 7280 so it is handled ONLY via the hot queue (threshold 7280).
#define TAB_N    1920
#define TAB_BASE 17792     // 0x4580 == bits(4096.f) >> 16

struct Coef { float c[19]; };  // c[k] = -log2(e)/(2*sigma_k)  (exp2 form)

#if defined(__has_builtin)
#if __has_builtin(__builtin_amdgcn_exp2f)
#define EXP2(x) __builtin_amdgcn_exp2f(x)
#else
#define EXP2(x) exp2f(x)
#endif
#else
#define EXP2(x) exp2f(x)
#endif

// --- kernel 1: E[a,b] = ||f_a - f_b||^2 for both sides, 16x16 tiles ---------
__global__ __launch_bounds__(256) void compute_E(const float* __restrict__ Fs,
                                                 const float* __restrict__ Ft,
                                                 float* __restrict__ ws) {
    int side = blockIdx.x / 100;          // 0 = source, 1 = target
    int tile = blockIdx.x % 100;
    int trow = tile / 10, tcol = tile % 10;
    const float* F = side ? Ft : Fs;
    float* E = ws + (side ? WS_ET : WS_ES);

    __shared__ float As[16][132];
    __shared__ float Bs[16][132];
    int tid = threadIdx.x;
    int ti = tid >> 4, tj = tid & 15;
    int lr = tid >> 5;        // 0..7
    int lc4 = tid & 31;       // float4 column (0..31) of 128-dim chunk

    float acc = 0.f;
    for (int ch = 0; ch < 8; ++ch) {
        for (int rr = lr; rr < 16; rr += 8) {
            float4 a = *(const float4*)(F + (trow*16+rr)*FEAT + ch*128 + lc4*4);
            *(float4*)(&As[rr][lc4*4]) = a;
            float4 b = *(const float4*)(F + (tcol*16+rr)*FEAT + ch*128 + lc4*4);
            *(float4*)(&Bs[rr][lc4*4]) = b;
        }
        __syncthreads();
        #pragma unroll
        for (int c = 0; c < 128; c += 4) {
            float4 a = *(const float4*)(&As[ti][c]);
            float4 b = *(const float4*)(&Bs[tj][c]);
            float d0 = a.x - b.x, d1 = a.y - b.y, d2 = a.z - b.z, d3 = a.w - b.w;
            acc = fmaf(d0, d0, acc);
            acc = fmaf(d1, d1, acc);
            acc = fmaf(d2, d2, acc);
            acc = fmaf(d3, d3, acc);
        }
        __syncthreads();
    }
    E[(trow*16+ti)*NROW + tcol*16 + tj] = acc;
}

// --- kernel 2: gather interleaved bci/wci rows; pad; zero accumulators ------
__global__ __launch_bounds__(256) void scatter(float* __restrict__ ws) {
    int idx = blockIdx.x * blockDim.x + threadIdx.x;
    const float* E_s = ws + WS_ES;
    const float* E_t = ws + WS_ET;
    float4* bci = (float4*)(ws + WS_BCI);
    float4* wci = (float4*)(ws + WS_WCI);
    double* accs = (double*)((char*)ws + WS_ACC_BYTES);

    if (idx < 6 * NSLOT) accs[idx] = 0.0;

    if (idx < NBC) {
        int t = idx >> 2, ii = idx & 3;
        int pi, pj;
        if (t == 0) { pi = 0; pj = 1; }
        else {
            int tt = t - 1;
            pi = 1 + tt / 39;
            int jj = tt % 39;
            pj = (jj < pi) ? jj : jj + 1;
        }
        bci[2*idx]   = *(const float4*)(E_s + (4*pi + ii)*NROW + 4*pj);
        bci[2*idx+1] = *(const float4*)(E_t + (4*pi + ii)*NROW + 4*pj);
    } else if (idx < NBC + NWC) {
        int r = idx - NBC;
        int p = r >> 2;
        wci[2*r]   = *(const float4*)(E_s + r*NROW + 4*p);
        wci[2*r+1] = *(const float4*)(E_t + r*NROW + 4*p);
    } else if (idx < NBC + NWC + 256) {
        int p = NBC + (idx - (NBC + NWC));
        float4 pad = make_float4(1e19f, 1e19f, 1e19f, 1e19f);
        bci[2*p] = pad;
        bci[2*p+1] = pad;
    } else if (idx < NBC + NWC + 512) {
        int p = NWC + (idx - (NBC + NWC + 256));
        float4 pad = make_float4(1e19f, 1e19f, 1e19f, 1e19f);
        wci[2*p] = pad;
        wci[2*p+1] = pad;
    }
}

// --- tail terms for hot pairs (d < 7280): sigma <= 35 tiers -----------------
// Tier-skip is exact: exp2(d*c) == 0.0f once d*c <= -150:
// sigma<=35 -> d>=7279; sigma<=15 -> d>=3120; sigma<=1 -> 208.
__device__ __forceinline__ float tail_sum(float d, const Coef& co) {
    float s = EXP2(d * co.c[10]) + EXP2(d * co.c[11])
            + EXP2(d * co.c[12]) + EXP2(d * co.c[13]);   // 20,25,30,35
    if (d < 3120.0f)
        s += EXP2(d * co.c[7]) + EXP2(d * co.c[8]) + EXP2(d * co.c[9]); // 5,10,15
    if (d < 208.0f)
        s += EXP2(d * co.c[0]) + EXP2(d * co.c[1]) + EXP2(d * co.c[2])
           + EXP2(d * co.c[3]) + EXP2(d * co.c[4]) + EXP2(d * co.c[5])
           + EXP2(d * co.c[6]);                           // sigma <= 1
    return s;
}

// exact big-5: sigma = 100, 1e3, 1e4, 1e5, 1e6 via direct hw exp
__device__ __forceinline__ float big5(float d, const Coef& co) {
    return EXP2(d * co.c[14]) + EXP2(d * co.c[15]) + EXP2(d * co.c[16])
         + EXP2(d * co.c[17]) + EXP2(d * co.c[18]);
}
// big-4 (table contents): sigma = 1e3, 1e4, 1e5, 1e6
__device__ __forceinline__ float big4(float d, const Coef& co) {
    return EXP2(d * co.c[15]) + EXP2(d * co.c[16])
         + EXP2(d * co.c[17]) + EXP2(d * co.c[18]);
}

__device__ __forceinline__ float sqd(float4 a, float4 b) {
    float d0 = a.x - b.x, d1 = a.y - b.y, d2 = a.z - b.z, d3 = a.w - b.w;
    float d = d0 * d0;
    d = fmaf(d1, d1, d);
    d = fmaf(d2, d2, d);
    return fmaf(d3, d3, d);
}

// --- kernel 3: balanced 4-row fused sweep with LDS PL table -----------------
// 1522 blocks; block b owns bc rows {b, 6087-b, 3043-b, 3044+b} (const total
// length 12174). Blocks 0..79 first do wc pair {b, 159-b} (queues flushed
// between phases); blocks 80..104 do one st-diagonal strip. Inline per eval:
// s_big via PL table (err <= ~2.5e-6, e2 excluded). Hot pairs (d<7280) go to
// 3 per-wave LDS queues; drain adds big5 + tail - table(d) so the inline
// (possibly clamped) table term cancels exactly.
__global__ __launch_bounds__(256, 6) void gk_fused4(float* __restrict__ ws, Coef co) {
    const float4* bci = (const float4*)(ws + WS_BCI);
    const float4* wci = (const float4*)(ws + WS_WCI);
    double* accs = (double*)((char*)ws + WS_ACC_BYTES);

    __shared__ float2 tabs[TAB_N];
    __shared__ float qb[4][3][192];
    __shared__ double wsum[4][6];

    int tid = threadIdx.x;
    int lane = tid & 63, w = tid >> 6;

    // build the PL table (midpoint-corrected chord per cell)
    for (int k = tid; k < TAB_N; k += 256) {
        unsigned u_lo = (unsigned)(TAB_BASE + k) << 16;
        float d_lo = __uint_as_float(u_lo);
        float d_mi = __uint_as_float(u_lo + 0x8000u);
        float d_hi = __uint_as_float(u_lo + 0x10000u);
        float f_lo = big4(d_lo, co);
        float f_mi = big4(d_mi, co);
        float f_hi = big4(d_hi, co);
        float del = f_hi - f_lo;
        float base = f_lo + 0.5f * (f_mi - 0.5f * (f_lo + f_hi));
        tabs[k] = make_float2(base, del * (1.0f / 65536.0f));
    }
    __syncthreads();

    auto tab_get = [&](float d) -> float {
        unsigned u = __float_as_uint(d);
        int t = (int)(u >> 16) - TAB_BASE;
        t = min(max(t, 0), TAB_N - 1);
        float fr = (float)(u & 0xFFFFu);
        float2 e = tabs[t];
        return fmaf(fr, e.y, e.x);
    };
    auto drain_term = [&](float d) -> float {
        return big5(d, co) + tail_sum(d, co) - tab_get(d);
    };

    int qn0 = 0, qn1 = 0, qn2 = 0;   // wave-uniform queue depths
    double a0 = 0.0, a1 = 0.0, a2 = 0.0, a3 = 0.0, a4 = 0.0, a5 = 0.0;

#define MBCNT(m) __builtin_amdgcn_mbcnt_hi((unsigned)((m) >> 32), \
                  __builtin_amdgcn_mbcnt_lo((unsigned)(m), 0u))
#define PUSHQ(Q, QN, dv) { bool hot_ = (dv) < 7280.0f;              \
        unsigned long long m_ = __ballot(hot_);                      \
        if (hot_) qb[w][Q][(QN) + MBCNT(m_)] = (dv);                 \
        (QN) += (int)__popcll(m_); }
#define DRAINQ(Q, QN, ACC) if ((QN) >= 64) { (QN) -= 64;             \
        ACC += drain_term(qb[w][Q][(QN) + lane]); }

    auto process = [&](const float4* __restrict__ Yv, int N, int i,
                       double& A0, double& A1, double& A2) {
        float4 xs = Yv[2*i], xt = Yv[2*i+1];
        int jbeg = i + 1;
        int trips = (N - jbeg + 255) >> 8;
        const float4* Yp = Yv + 2*(jbeg + tid);
        float m0 = 0.f, m1 = 0.f, m2 = 0.f;
        for (int t = 0; t < trips; ++t) {
            float4 ys = Yp[0], yt = Yp[1];
            Yp += 512;
            float dss = sqd(xs, ys), dtt = sqd(xt, yt);
            float dst = sqd(xs, yt), dts = sqd(xt, ys);
            m0 += tab_get(dss);
            m1 += tab_get(dtt);
            m2 += tab_get(dst) + tab_get(dts);
            PUSHQ(0, qn0, dss); DRAINQ(0, qn0, m0);
            PUSHQ(1, qn1, dtt); DRAINQ(1, qn1, m1);
            PUSHQ(2, qn2, dst); DRAINQ(2, qn2, m2);
            PUSHQ(2, qn2, dts); DRAINQ(2, qn2, m2);
        }
        A0 += (double)m0; A1 += (double)m1; A2 += (double)m2;
    };

    int b = blockIdx.x;

    // st-diagonal strips (blocks 80..104): no queue use
    if (b >= 80 && b < 105) {
        int s = b - 80;
        if (s < 24) {
            int i0 = s * 256 + tid;
            if (i0 < NBC) {
                float d = sqd(bci[2*i0], bci[2*i0+1]);
                float sv = big5(d, co);
                if (d < 7280.0f) sv += tail_sum(d, co);
                a5 += (double)sv;
            }
        } else {
            if (tid < NWC) {
                float d = sqd(wci[2*tid], wci[2*tid+1]);
                float sv = big5(d, co);
                if (d < 7280.0f) sv += tail_sum(d, co);
                a2 += (double)sv;
            }
        }
    }

    // wc pairs (blocks 0..79), then flush queues before reusing them for bc
    if (b < 80) {
        process(wci, NWC, b,          a0, a1, a2);
        process(wci, NWC, NWC - 1 - b, a0, a1, a2);
        if (lane < qn0) a0 += (double)drain_term(qb[w][0][lane]);
        if (lane < qn1) a1 += (double)drain_term(qb[w][1][lane]);
        if (lane < qn2) a2 += (double)drain_term(qb[w][2][lane]);
        qn0 = qn1 = qn2 = 0;
    }

    // bc rows: {b, 6087-b, 3043-b, 3044+b} — constant total work
    process(bci, NBC, b,        a3, a4, a5);
    process(bci, NBC, 6087 - b, a3, a4, a5);
    process(bci, NBC, 3043 - b, a3, a4, a5);
    process(bci, NBC, 3044 + b, a3, a4, a5);
    if (lane < qn0) a3 += (double)drain_term(qb[w][0][lane]);
    if (lane < qn1) a4 += (double)drain_term(qb[w][1][lane]);
    if (lane < qn2) a5 += (double)drain_term(qb[w][2][lane]);

    // wave reduce, then block reduce 4 waves, 6 jobs
    #pragma unroll
    for (int off = 32; off; off >>= 1) {
        a0 += __shfl_down(a0, off, 64);
        a1 += __shfl_down(a1, off, 64);
        a2 += __shfl_down(a2, off, 64);
        a3 += __shfl_down(a3, off, 64);
        a4 += __shfl_down(a4, off, 64);
        a5 += __shfl_down(a5, off, 64);
    }
    if (lane == 0) {
        wsum[w][0] = a0; wsum[w][1] = a1; wsum[w][2] = a2;
        wsum[w][3] = a3; wsum[w][4] = a4; wsum[w][5] = a5;
    }
    __syncthreads();
    if (tid < 6) {
        int q = tid;
        double tot = wsum[0][q] + wsum[1][q] + wsum[2][q] + wsum[3][q];
        atomicAdd(&accs[q * NSLOT + (b & (NSLOT - 1))], tot);
    }
#undef PUSHQ
#undef DRAINQ
#undef MBCNT
}

// --- kernel 4: combine into the two output scalars --------------------------
__global__ void finalize(const float* __restrict__ ws, float* __restrict__ out) {
    const double* accs = (const double*)((const char*)ws + WS_ACC_BYTES);
    int lane = threadIdx.x;  // blockDim = 64
    double p[6];
    #pragma unroll
    for (int q = 0; q < 6; ++q) {
        p[q] = accs[q * NSLOT + lane];
        #pragma unroll
        for (int off = 32; off; off >>= 1) p[q] += __shfl_down(p[q], off, 64);
    }
    if (lane == 0) {
        double t0 = 2.0 * p[0] + 19.0 * NWC;   // self: 2*triangle + diag
        double t1 = 2.0 * p[1] + 19.0 * NWC;
        double t3 = 2.0 * p[3] + 19.0 * NBC;
        double t4 = 2.0 * p[4] + 19.0 * NBC;
        double nw = (double)NWC * (double)NWC;
        double nb = (double)NBC * (double)NBC;
        out[0] = (float)((t0 + t1 - 2.0 * p[2]) / nw);   // p2 = full st sum
        out[1] = (float)((t3 + t4 - 2.0 * p[5]) / nb);
    }
}

extern "C" void kernel_launch(void* const* d_in, const int* in_sizes, int n_in,
                              void* d_out, int out_size, void* d_ws, size_t ws_size,
                              hipStream_t stream) {
    const float* src = (const float*)d_in[0];
    const float* tgt = (const float*)d_in[1];
    float* out = (float*)d_out;
    float* ws = (float*)d_ws;

    static const double SIG[19] = {1e-06, 1e-05, 1e-04, 1e-03, 1e-02, 1e-01,
                                   1.0, 5.0, 10.0, 15.0, 20.0, 25.0, 30.0,
                                   35.0, 100.0, 1e3, 1e4, 1e5, 1e6};
    Coef co;
    for (int k = 0; k < 19; ++k)
        co.c[k] = (float)(-1.0 / (2.0 * SIG[k] * 0.6931471805599453));  // -log2e/(2s)

    compute_E<<<200, 256, 0, stream>>>(src, tgt, ws);
    scatter<<<27, 256, 0, stream>>>(ws);
    gk_fused4<<<GK_BLOCKS, 256, 0, stream>>>(ws, co);
    finalize<<<1, 64, 0, stream>>>(ws, out);
}

// Round 9
// 66.959 us; speedup vs baseline: 1.3227x; 1.1059x over previous
//
#include <hip/hip_runtime.h>

// ---------------------------------------------------------------------------
// MaximumMeanDiscrepancy: BATCH=160, INSTANCES=4, FEAT=1024, P=40
// out[0] = mmd(wcs, wct), out[1] = mmd(bcs, bct)
// ---------------------------------------------------------------------------

#define FEAT   1024
#define NROW   160     // BATCH
#define NBC    6088    // (1 + 39*39) * 4
#define NWC    160

// workspace layout (float offsets). bci/wci INTERLEAVED: row i = {src f4, tgt f4}.
// 256 pad rows of 1e19f follow each array (pad d -> inf -> top table cell
// ~1e-29, never hot). The global PL table lives in the dead E_t region
// (E dead after scatter; build_tab runs after scatter).
#define WS_ES   0          // E_s [160*160]
#define WS_ET   25600      // E_t [160*160]  (later: PL table float2[2048])
#define WS_TAB  25600
#define WS_BCI  51200      // bci [(6088+256)*8]
#define WS_WCI  101952     // wci [(160+256)*8]
#define WS_ACC_BYTES 421120  // 6*64 doubles
#define NSLOT  64

// PL table: sum of sigma in {20,25,30,35,100,1e3,1e4,1e5,1e6} over d in
// [2048, 2^27), 128 cells/octave, bits-indexed by (float_bits>>16)-17664.
// hot (queue) threshold: cell t < 67  <=>  d < 3120.0f (sigma<=15 nonzero
// only below 3119.1; d<2048 is below table domain so it must be hot: ok).
#define TAB_N    2048
#define TAB_BASE 17664     // bits(2048.f) >> 16
#define HOT_CELL 67

// gk grid: bc pair-parity blocks, then wc pairs, then diag strips
#define GK_BC    6088      // pair i = b>>1 (rows {i, 6087-i}), parity b&1
#define GK_WC    80        // rows {b, 159-b}
#define GK_GRID  6193      // + 24 bc-diag strips + 1 wc-diag

struct Coef { float c[19]; };  // c[k] = -log2(e)/(2*sigma_k)  (exp2 form)

#if defined(__has_builtin)
#if __has_builtin(__builtin_amdgcn_exp2f)
#define EXP2(x) __builtin_amdgcn_exp2f(x)
#else
#define EXP2(x) exp2f(x)
#endif
#else
#define EXP2(x) exp2f(x)
#endif

// --- kernel 1: E[a,b] = ||f_a - f_b||^2 for both sides, 16x16 tiles ---------
__global__ __launch_bounds__(256) void compute_E(const float* __restrict__ Fs,
                                                 const float* __restrict__ Ft,
                                                 float* __restrict__ ws) {
    int side = blockIdx.x / 100;          // 0 = source, 1 = target
    int tile = blockIdx.x % 100;
    int trow = tile / 10, tcol = tile % 10;
    const float* F = side ? Ft : Fs;
    float* E = ws + (side ? WS_ET : WS_ES);

    __shared__ float As[16][132];
    __shared__ float Bs[16][132];
    int tid = threadIdx.x;
    int ti = tid >> 4, tj = tid & 15;
    int lr = tid >> 5;        // 0..7
    int lc4 = tid & 31;       // float4 column (0..31) of 128-dim chunk

    float acc = 0.f;
    for (int ch = 0; ch < 8; ++ch) {
        for (int rr = lr; rr < 16; rr += 8) {
            float4 a = *(const float4*)(F + (trow*16+rr)*FEAT + ch*128 + lc4*4);
            *(float4*)(&As[rr][lc4*4]) = a;
            float4 b = *(const float4*)(F + (tcol*16+rr)*FEAT + ch*128 + lc4*4);
            *(float4*)(&Bs[rr][lc4*4]) = b;
        }
        __syncthreads();
        #pragma unroll
        for (int c = 0; c < 128; c += 4) {
            float4 a = *(const float4*)(&As[ti][c]);
            float4 b = *(const float4*)(&Bs[tj][c]);
            float d0 = a.x - b.x, d1 = a.y - b.y, d2 = a.z - b.z, d3 = a.w - b.w;
            acc = fmaf(d0, d0, acc);
            acc = fmaf(d1, d1, acc);
            acc = fmaf(d2, d2, acc);
            acc = fmaf(d3, d3, acc);
        }
        __syncthreads();
    }
    E[(trow*16+ti)*NROW + tcol*16 + tj] = acc;
}

// --- kernel 2: gather interleaved bci/wci rows; pad; zero accumulators ------
__global__ __launch_bounds__(256) void scatter(float* __restrict__ ws) {
    int idx = blockIdx.x * blockDim.x + threadIdx.x;
    const float* E_s = ws + WS_ES;
    const float* E_t = ws + WS_ET;
    float4* bci = (float4*)(ws + WS_BCI);
    float4* wci = (float4*)(ws + WS_WCI);
    double* accs = (double*)((char*)ws + WS_ACC_BYTES);

    if (idx < 6 * NSLOT) accs[idx] = 0.0;

    if (idx < NBC) {
        int t = idx >> 2, ii = idx & 3;
        int pi, pj;
        if (t == 0) { pi = 0; pj = 1; }
        else {
            int tt = t - 1;
            pi = 1 + tt / 39;
            int jj = tt % 39;
            pj = (jj < pi) ? jj : jj + 1;
        }
        bci[2*idx]   = *(const float4*)(E_s + (4*pi + ii)*NROW + 4*pj);
        bci[2*idx+1] = *(const float4*)(E_t + (4*pi + ii)*NROW + 4*pj);
    } else if (idx < NBC + NWC) {
        int r = idx - NBC;
        int p = r >> 2;
        wci[2*r]   = *(const float4*)(E_s + r*NROW + 4*p);
        wci[2*r+1] = *(const float4*)(E_t + r*NROW + 4*p);
    } else if (idx < NBC + NWC + 256) {
        int p = NBC + (idx - (NBC + NWC));
        float4 pad = make_float4(1e19f, 1e19f, 1e19f, 1e19f);
        bci[2*p] = pad;
        bci[2*p+1] = pad;
    } else if (idx < NBC + NWC + 512) {
        int p = NWC + (idx - (NBC + NWC + 256));
        float4 pad = make_float4(1e19f, 1e19f, 1e19f, 1e19f);
        wci[2*p] = pad;
        wci[2*p+1] = pad;
    }
}

// --- exact term helpers ------------------------------------------------------
// Tier-skip is exact: exp2(d*c) == 0.0f once d*c <= -150:
// sigma<=35 -> d>=7279; sigma<=15 -> d>=3120; sigma<=1 -> 208.
__device__ __forceinline__ float tail_sum(float d, const Coef& co) {
    float s = EXP2(d * co.c[10]) + EXP2(d * co.c[11])
            + EXP2(d * co.c[12]) + EXP2(d * co.c[13]);   // 20,25,30,35
    if (d < 3120.0f)
        s += EXP2(d * co.c[7]) + EXP2(d * co.c[8]) + EXP2(d * co.c[9]); // 5,10,15
    if (d < 208.0f)
        s += EXP2(d * co.c[0]) + EXP2(d * co.c[1]) + EXP2(d * co.c[2])
           + EXP2(d * co.c[3]) + EXP2(d * co.c[4]) + EXP2(d * co.c[5])
           + EXP2(d * co.c[6]);                           // sigma <= 1
    return s;
}
// big-5: sigma = 100, 1e3, 1e4, 1e5, 1e6 (exact)
__device__ __forceinline__ float big5(float d, const Coef& co) {
    return EXP2(d * co.c[14]) + EXP2(d * co.c[15]) + EXP2(d * co.c[16])
         + EXP2(d * co.c[17]) + EXP2(d * co.c[18]);
}
// big-9 (table contents): sigma = 20..35, 100, 1e3..1e6
__device__ __forceinline__ float big9(float d, const Coef& co) {
    float s = 0.f;
    #pragma unroll
    for (int k = 10; k < 19; ++k) s += EXP2(d * co.c[k]);
    return s;
}

__device__ __forceinline__ float sqd(float4 a, float4 b) {
    float d0 = a.x - b.x, d1 = a.y - b.y, d2 = a.z - b.z, d3 = a.w - b.w;
    float d = d0 * d0;
    d = fmaf(d1, d1, d);
    d = fmaf(d2, d2, d);
    return fmaf(d3, d3, d);
}

// --- kernel 2b: build the global PL table (dead E_t region) -----------------
// midpoint-corrected chord per cell; cells never cross an exponent boundary
// so d is linear in mantissa bits within a cell.
__global__ __launch_bounds__(256) void build_tab(float* __restrict__ ws, Coef co) {
    int k = blockIdx.x * 256 + threadIdx.x;
    if (k >= TAB_N) return;
    unsigned u_lo = (unsigned)(TAB_BASE + k) << 16;
    float d_lo = __uint_as_float(u_lo);
    float d_mi = __uint_as_float(u_lo + 0x8000u);
    float d_hi = __uint_as_float(u_lo + 0x10000u);
    float f_lo = big9(d_lo, co), f_mi = big9(d_mi, co), f_hi = big9(d_hi, co);
    float2 e;
    e.x = f_lo + 0.5f * (f_mi - 0.5f * (f_lo + f_hi));
    e.y = (f_hi - f_lo) * (1.0f / 65536.0f);
    ((float2*)(ws + WS_TAB))[k] = e;
}

// --- kernel 3: fill-friendly fused sweep ------------------------------------
// bc blocks (b<6088): pair i=b>>1 -> rows {i, 6087-i}, trip-parity b&1
//   (constant ~12 trips/block). wc blocks: rows {i,159-i} full. diag blocks:
//   one 256-wide strip of k(s_i,t_i), exact path.
// Per trip: 2 f4 loads, 4 sqd, 4 table lookups (zero inline exps). Hot pairs
// (cell<67 ~0.43%/eval) -> 3 per-wave LDS queues (ballot+mbcnt), drained
// 64-wide; drain adds big5+tail-tab(d) so the inline lookup cancels exactly.
__global__ __launch_bounds__(256, 7) void gk_main(float* __restrict__ ws, Coef co) {
    const float4* bci = (const float4*)(ws + WS_BCI);
    const float4* wci = (const float4*)(ws + WS_WCI);
    double* accs = (double*)((char*)ws + WS_ACC_BYTES);

    __shared__ float4 tabs4[TAB_N / 2];
    __shared__ float qb[4][3][128];
    __shared__ double wsum[4][3];
    const float2* tabs = (const float2*)tabs4;

    int tid = threadIdx.x;
    int lane = tid & 63, w = tid >> 6;

    {   // copy PL table global -> LDS (4 x float4 per thread)
        const float4* tg = (const float4*)(ws + WS_TAB);
        for (int k = tid; k < TAB_N / 2; k += 256) tabs4[k] = tg[k];
    }
    __syncthreads();

    auto tab_get = [&](float d) -> float {
        unsigned u = __float_as_uint(d);
        int t = (int)(u >> 16) - TAB_BASE;
        t = min(max(t, 0), TAB_N - 1);
        float fr = (float)(u & 0xFFFFu);
        float2 e = tabs[t];
        return fmaf(fr, e.y, e.x);
    };
    auto drain_term = [&](float d) -> float {
        return big5(d, co) + tail_sum(d, co) - tab_get(d);
    };

    int qn0 = 0, qn1 = 0, qn2 = 0;
    double a0 = 0.0, a1 = 0.0, a2 = 0.0;

#define MBCNT(m) __builtin_amdgcn_mbcnt_hi((unsigned)((m) >> 32), \
                  __builtin_amdgcn_mbcnt_lo((unsigned)(m), 0u))
    // eval: table accumulate + hot push (+ dense drain when a queue fills)
#define EVAL1(dv, M, Q, QN) { \
        unsigned u_ = __float_as_uint(dv); \
        int t_ = (int)(u_ >> 16) - TAB_BASE; \
        bool hot_ = t_ < HOT_CELL; \
        t_ = min(max(t_, 0), TAB_N - 1); \
        float2 e_ = tabs[t_]; \
        M = fmaf((float)(u_ & 0xFFFFu), e_.y, e_.x) + M; \
        unsigned long long m_ = __ballot(hot_); \
        if (hot_) qb[w][Q][(QN) + MBCNT(m_)] = (dv); \
        (QN) += (int)__popcll(m_); \
        if ((QN) >= 64) { (QN) -= 64; M += drain_term(qb[w][Q][(QN) + lane]); } }

    auto process = [&](const float4* __restrict__ Yv, int N, int i,
                       int par, bool half) {
        int jbeg = i + 1;
        int T = (N - jbeg + 255) >> 8;
        int trips = half ? ((T - par + 1) >> 1) : T;
        if (trips <= 0) return;
        float4 xs = Yv[2*i], xt = Yv[2*i+1];
        const float4* Yp = Yv + 2*(jbeg + par*256 + tid);
        int stride = half ? 1024 : 512;
        float m0 = 0.f, m1 = 0.f, m2 = 0.f;
        for (int t = 0; t < trips; ++t) {
            float4 ys = Yp[0], yt = Yp[1];
            Yp += stride;
            float dss = sqd(xs, ys), dtt = sqd(xt, yt);
            float dst = sqd(xs, yt), dts = sqd(xt, ys);
            EVAL1(dss, m0, 0, qn0);
            EVAL1(dtt, m1, 1, qn1);
            EVAL1(dst, m2, 2, qn2);
            EVAL1(dts, m2, 2, qn2);
        }
        a0 += (double)m0; a1 += (double)m1; a2 += (double)m2;
    };

    int b = blockIdx.x;
    int jb;  // job base: wc jobs 0..2, bc jobs 3..5
    if (b < GK_BC) {
        int i = b >> 1, par = b & 1;
        jb = 3;
        process(bci, NBC, i,        par, true);
        process(bci, NBC, 6087 - i, par, true);
    } else if (b < GK_BC + GK_WC) {
        int i = b - GK_BC;
        jb = 0;
        process(wci, NWC, i,        0, false);
        process(wci, NWC, 159 - i,  0, false);
    } else {
        int s = b - (GK_BC + GK_WC);   // 0..24
        if (s < 24) {
            jb = 3;                    // st-diag of bc -> job 5 (= jb + 2)
            int i0 = s * 256 + tid;
            if (i0 < NBC) {
                float d = sqd(bci[2*i0], bci[2*i0+1]);
                float sv = big5(d, co);
                if (d < 7280.0f) sv += tail_sum(d, co);
                a2 += (double)sv;
            }
        } else {
            jb = 0;                    // st-diag of wc -> job 2
            if (tid < NWC) {
                float d = sqd(wci[2*tid], wci[2*tid+1]);
                float sv = big5(d, co);
                if (d < 7280.0f) sv += tail_sum(d, co);
                a2 += (double)sv;
            }
        }
    }

    // flush remaining queue entries (< 64 each)
    if (lane < qn0) a0 += (double)drain_term(qb[w][0][lane]);
    if (lane < qn1) a1 += (double)drain_term(qb[w][1][lane]);
    if (lane < qn2) a2 += (double)drain_term(qb[w][2][lane]);

    // wave reduce, then block reduce 4 waves, 3 jobs
    #pragma unroll
    for (int off = 32; off; off >>= 1) {
        a0 += __shfl_down(a0, off, 64);
        a1 += __shfl_down(a1, off, 64);
        a2 += __shfl_down(a2, off, 64);
    }
    if (lane == 0) { wsum[w][0] = a0; wsum[w][1] = a1; wsum[w][2] = a2; }
    __syncthreads();
    if (tid < 3) {
        double tot = wsum[0][tid] + wsum[1][tid] + wsum[2][tid] + wsum[3][tid];
        atomicAdd(&accs[(jb + tid) * NSLOT + (b & (NSLOT - 1))], tot);
    }
#undef EVAL1
#undef MBCNT
}

// --- kernel 4: combine into the two output scalars --------------------------
__global__ void finalize(const float* __restrict__ ws, float* __restrict__ out) {
    const double* accs = (const double*)((const char*)ws + WS_ACC_BYTES);
    int lane = threadIdx.x;  // blockDim = 64
    double p[6];
    #pragma unroll
    for (int q = 0; q < 6; ++q) {
        p[q] = accs[q * NSLOT + lane];
        #pragma unroll
        for (int off = 32; off; off >>= 1) p[q] += __shfl_down(p[q], off, 64);
    }
    if (lane == 0) {
        double t0 = 2.0 * p[0] + 19.0 * NWC;   // self: 2*triangle + diag
        double t1 = 2.0 * p[1] + 19.0 * NWC;
        double t3 = 2.0 * p[3] + 19.0 * NBC;
        double t4 = 2.0 * p[4] + 19.0 * NBC;
        double nw = (double)NWC * (double)NWC;
        double nb = (double)NBC * (double)NBC;
        out[0] = (float)((t0 + t1 - 2.0 * p[2]) / nw);   // p2 = full st sum
        out[1] = (float)((t3 + t4 - 2.0 * p[5]) / nb);
    }
}

extern "C" void kernel_launch(void* const* d_in, const int* in_sizes, int n_in,
                              void* d_out, int out_size, void* d_ws, size_t ws_size,
                              hipStream_t stream) {
    const float* src = (const float*)d_in[0];
    const float* tgt = (const float*)d_in[1];
    float* out = (float*)d_out;
    float* ws = (float*)d_ws;

    static const double SIG[19] = {1e-06, 1e-05, 1e-04, 1e-03, 1e-02, 1e-01,
                                   1.0, 5.0, 10.0, 15.0, 20.0, 25.0, 30.0,
                                   35.0, 100.0, 1e3, 1e4, 1e5, 1e6};
    Coef co;
    for (int k = 0; k < 19; ++k)
        co.c[k] = (float)(-1.0 / (2.0 * SIG[k] * 0.6931471805599453));  // -log2e/(2s)

    compute_E<<<200, 256, 0, stream>>>(src, tgt, ws);
    scatter<<<27, 256, 0, stream>>>(ws);
    build_tab<<<8, 256, 0, stream>>>(ws, co);
    gk_main<<<GK_GRID, 256, 0, stream>>>(ws, co);
    finalize<<<1, 64, 0, stream>>>(ws, out);
}